// Round 3
// baseline (204.044 us; speedup 1.0000x reference)
//
#include <hip/hip_runtime.h>
#include <math.h>

// Problem shape (fixed by setup_inputs): x (32,1024,1024) f32, weight (1024,1024) f32,
// bias (1024,) f32, out (32,1,1024) f32.
//
// Semantics: fix_x(x) = clamp(floor(32x)/32, -127/32, 127/32). All post-fix values are
// k/32 with k in [-127,127] -> exact integer domain. The scan is a saturating integer
// fold, parallelized via the clamped-shift-function monoid:
//   f(a)=clamp(a+s,L,U);  (G∘F) = (sF+sG, clamp(LF+sG,LG,UG), clamp(UF+sG,LG,UG))
// init folds in as constant fn (0,v,v) so the total composition has L==U==acc.
//
// R1/R2: XCD-aware swizzle (blk&7 = XCD heuristic) so all 8 blocks sharing a weight row
// land on one XCD -> w fetched once per XCD (32MB -> 4MB HBM). Nontemporal loads on
// the read-once x stream keep w L2-resident. R2 fixes the nontemporal builtin's operand
// type (needs a native ext_vector_type, not HIP_vector_type).

#define IN_DIM  1024
#define OUT_DIM 1024
#define B_DIM   32

typedef float vfloat4 __attribute__((ext_vector_type(4)));

__global__ __launch_bounds__(256) void ffl_kernel(
    const float* __restrict__ x,
    const float* __restrict__ w,
    const float* __restrict__ bias,
    float* __restrict__ out)
{
    const int lane = threadIdx.x & 63;
    const int wid  = threadIdx.x >> 6;

    // 8192 blocks. xcd = blk&7 owns o in [xcd*128, xcd*128+128).
    const int xcd = blockIdx.x & 7;
    const int j   = blockIdx.x >> 3;          // 0..1023
    const int o   = (xcd << 7) | (j >> 3);    // 128 o-rows per XCD band
    const int b   = (((j & 7) << 2) | wid);   // 8 subs * 4 waves = 32 b-values

    const vfloat4* xp = (const vfloat4*)(x + ((size_t)b * OUT_DIM + o) * IN_DIM + lane * 16);
    const vfloat4* wp = (const vfloat4*)(w + (size_t)o * IN_DIM + lane * 16);

    // running composed function (identity), built over this lane's 16 contiguous elems
    int rs = 0;
    int rL = -(1 << 28);
    int rU =  (1 << 28);

    #pragma unroll
    for (int jj = 0; jj < 4; ++jj) {
        vfloat4 xv = __builtin_nontemporal_load(&xp[jj]);  // read-once stream: nt bit
        vfloat4 wv = wp[jj];                               // reused across 32 waves: cache
        float pe[4] = { xv.x * wv.x, xv.y * wv.y, xv.z * wv.z, xv.w * wv.w };
        #pragma unroll
        for (int e = 0; e < 4; ++e) {
            // quantize: v = clamp(floor(32 * (x*w)), -127, 127)
            // (x*w) rounds first (matches JAX); *32 and /32 are exact (pow2).
            // clamp in fp32 -> v_med3_f32, single cvt to int.
            float t = floorf(pe[e] * 32.0f);
            t = fminf(fmaxf(t, -127.0f), 127.0f);
            int v = (int)t;
            // element i=1023 is the scan init -> constant function (0, v, v)
            bool isInit = (jj == 3) && (e == 3) && (lane == 63);
            int sE = isInit ? 0 : v;
            int LE = isInit ? v : -127;
            int UE = isInit ? v : 127;
            // new = running ∘ elem  (running outer: lower index applied later)
            int ns = sE + rs;
            int nL = min(max(LE + rs, rL), rU);   // -> v_med3_i32
            int nU = min(max(UE + rs, rL), rU);
            rs = ns; rL = nL; rU = nU;
        }
    }

    // 6-step butterfly: lane with lower block index is the OUTER function.
    // After the loop every lane holds the total composition; since the constant
    // init function is innermost, L == U == acc.
    #pragma unroll
    for (int m = 1; m < 64; m <<= 1) {
        int ps = __shfl_xor(rs, m, 64);
        int pL = __shfl_xor(rL, m, 64);
        int pU = __shfl_xor(rU, m, 64);
        bool lower = ((lane & m) == 0);
        int sG = lower ? rs : ps;   // outer
        int LG = lower ? rL : pL;
        int UG = lower ? rU : pU;
        int sF = lower ? ps : rs;   // inner
        int LF = lower ? pL : rL;
        int UF = lower ? pU : rU;
        rs = sF + sG;
        rL = min(max(LF + sG, LG), UG);
        rU = min(max(UF + sG, LG), UG);
    }

    if (lane == 0) {
        // acc (= rL = rU) is exact; final: fix_x(acc/32 + bias) in fp32 like the ref
        float acc = (float)rL * 0.03125f;          // exact (power of 2)
        float tb  = acc + bias[o];                 // single fp32 rounding, matches ref
        float r   = floorf(tb * 32.0f);            // *32 exact
        r = fminf(fmaxf(r, -127.0f), 127.0f);
        out[(size_t)b * OUT_DIM + o] = r * 0.03125f;
    }
}

extern "C" void kernel_launch(void* const* d_in, const int* in_sizes, int n_in,
                              void* d_out, int out_size, void* d_ws, size_t ws_size,
                              hipStream_t stream) {
    const float* x    = (const float*)d_in[0];
    const float* w    = (const float*)d_in[1];
    const float* bias = (const float*)d_in[2];
    float* out = (float*)d_out;

    const int pairs  = B_DIM * OUT_DIM;    // 32768 (b,o) pairs, one wave each
    const int blocks = pairs / 4;          // 4 waves per 256-thread block
    ffl_kernel<<<blocks, 256, 0, stream>>>(x, w, bias, out);
}

// Round 4
// 195.815 us; speedup vs baseline: 1.0420x; 1.0420x over previous
//
#include <hip/hip_runtime.h>
#include <math.h>

// Problem shape (fixed by setup_inputs): x (32,1024,1024) f32, weight (1024,1024) f32,
// bias (1024,) f32, out (32,1,1024) f32.
//
// Semantics: fix_x(x) = clamp(floor(32x)/32, -127/32, 127/32). All post-fix values are
// k/32 with k in [-127,127] -> exact integer domain. The scan is a saturating integer
// fold, parallelized via the clamped-shift-function monoid:
//   f(a)=clamp(a+s,L,U);  (G∘F) = (sF+sG, clamp(LF+sG,LG,UG), clamp(UF+sG,LG,UG))
// init folds in as constant fn (0,v,v) so the total composition has L==U==acc.
//
// R1/R2: XCD-aware swizzle (blk&7 = XCD heuristic) so all 8 blocks sharing a weight row
// land on one XCD -> w fetched once per XCD (32MB -> 4MB HBM).
// R3: revert the nontemporal hint on x (R2 regressed 194->204 us; nt evict-first
// plausibly hurt line reuse across the two adjacent float4 loads per lane). Plain
// global_load_dwordx4 for both streams; swizzle kept.

#define IN_DIM  1024
#define OUT_DIM 1024
#define B_DIM   32

typedef float vfloat4 __attribute__((ext_vector_type(4)));

__global__ __launch_bounds__(256) void ffl_kernel(
    const float* __restrict__ x,
    const float* __restrict__ w,
    const float* __restrict__ bias,
    float* __restrict__ out)
{
    const int lane = threadIdx.x & 63;
    const int wid  = threadIdx.x >> 6;

    // 8192 blocks. xcd = blk&7 owns o in [xcd*128, xcd*128+128).
    const int xcd = blockIdx.x & 7;
    const int j   = blockIdx.x >> 3;          // 0..1023
    const int o   = (xcd << 7) | (j >> 3);    // 128 o-rows per XCD band
    const int b   = (((j & 7) << 2) | wid);   // 8 subs * 4 waves = 32 b-values

    const vfloat4* xp = (const vfloat4*)(x + ((size_t)b * OUT_DIM + o) * IN_DIM + lane * 16);
    const vfloat4* wp = (const vfloat4*)(w + (size_t)o * IN_DIM + lane * 16);

    // running composed function (identity), built over this lane's 16 contiguous elems
    int rs = 0;
    int rL = -(1 << 28);
    int rU =  (1 << 28);

    #pragma unroll
    for (int jj = 0; jj < 4; ++jj) {
        vfloat4 xv = xp[jj];
        vfloat4 wv = wp[jj];
        float pe[4] = { xv.x * wv.x, xv.y * wv.y, xv.z * wv.z, xv.w * wv.w };
        #pragma unroll
        for (int e = 0; e < 4; ++e) {
            // quantize: v = clamp(floor(32 * (x*w)), -127, 127)
            // (x*w) rounds first (matches JAX); *32 and /32 are exact (pow2).
            // clamp in fp32 -> v_med3_f32, single cvt to int.
            float t = floorf(pe[e] * 32.0f);
            t = fminf(fmaxf(t, -127.0f), 127.0f);
            int v = (int)t;
            // element i=1023 is the scan init -> constant function (0, v, v)
            bool isInit = (jj == 3) && (e == 3) && (lane == 63);
            int sE = isInit ? 0 : v;
            int LE = isInit ? v : -127;
            int UE = isInit ? v : 127;
            // new = running ∘ elem  (running outer: lower index applied later)
            int ns = sE + rs;
            int nL = min(max(LE + rs, rL), rU);   // -> v_med3_i32
            int nU = min(max(UE + rs, rL), rU);
            rs = ns; rL = nL; rU = nU;
        }
    }

    // 6-step butterfly: lane with lower block index is the OUTER function.
    // After the loop every lane holds the total composition; since the constant
    // init function is innermost, L == U == acc.
    #pragma unroll
    for (int m = 1; m < 64; m <<= 1) {
        int ps = __shfl_xor(rs, m, 64);
        int pL = __shfl_xor(rL, m, 64);
        int pU = __shfl_xor(rU, m, 64);
        bool lower = ((lane & m) == 0);
        int sG = lower ? rs : ps;   // outer
        int LG = lower ? rL : pL;
        int UG = lower ? rU : pU;
        int sF = lower ? ps : rs;   // inner
        int LF = lower ? pL : rL;
        int UF = lower ? pU : rU;
        rs = sF + sG;
        rL = min(max(LF + sG, LG), UG);
        rU = min(max(UF + sG, LG), UG);
    }

    if (lane == 0) {
        // acc (= rL = rU) is exact; final: fix_x(acc/32 + bias) in fp32 like the ref
        float acc = (float)rL * 0.03125f;          // exact (power of 2)
        float tb  = acc + bias[o];                 // single fp32 rounding, matches ref
        float r   = floorf(tb * 32.0f);            // *32 exact
        r = fminf(fmaxf(r, -127.0f), 127.0f);
        out[(size_t)b * OUT_DIM + o] = r * 0.03125f;
    }
}

extern "C" void kernel_launch(void* const* d_in, const int* in_sizes, int n_in,
                              void* d_out, int out_size, void* d_ws, size_t ws_size,
                              hipStream_t stream) {
    const float* x    = (const float*)d_in[0];
    const float* w    = (const float*)d_in[1];
    const float* bias = (const float*)d_in[2];
    float* out = (float*)d_out;

    const int pairs  = B_DIM * OUT_DIM;    // 32768 (b,o) pairs, one wave each
    const int blocks = pairs / 4;          // 4 waves per 256-thread block
    ffl_kernel<<<blocks, 256, 0, stream>>>(x, w, bias, out);
}

// Round 5
// 193.950 us; speedup vs baseline: 1.0520x; 1.0096x over previous
//
#include <hip/hip_runtime.h>
#include <math.h>

// Problem shape (fixed by setup_inputs): x (32,1024,1024) f32, weight (1024,1024) f32,
// bias (1024,) f32, out (32,1,1024) f32.
//
// Semantics: fix_x(x) = clamp(floor(32x)/32, -127/32, 127/32). All post-fix values are
// k/32 with k in [-127,127] -> exact integer domain. The scan is a saturating integer
// fold, parallelized via the clamped-shift-function monoid:
//   f(a)=clamp(a+s,L,U);  (G∘F) = (sF+sG, clamp(LF+sG,LG,UG), clamp(UF+sG,LG,UG))
// init (elem 1023) folds in as constant fn (0,v,v) so the total has L==U==acc.
// Element 0's function is OUTERMOST (scan processes 1022..0 after init=1023).
//
// R4: coalescing restructure. One block = one (b,o) row; 4 waves x 256 elems;
// lane i of wave wid owns elems [wid*256+4i, +4) -> each wave issues ONE fully
// coalesced 1KB dwordx4 load per stream (was: stride-64B lanes, 4x the L1
// transactions). Wave-local compose + 6-step butterfly per wave, then a 12-int
// LDS exchange and thread-0 composes the 4 chunk functions (chunk 3 innermost).
// XCD swizzle kept (blocks sharing a weight row land on one XCD).

#define IN_DIM  1024
#define OUT_DIM 1024
#define B_DIM   32

typedef float vfloat4 __attribute__((ext_vector_type(4)));

__global__ __launch_bounds__(256) void ffl_kernel(
    const float* __restrict__ x,
    const float* __restrict__ w,
    const float* __restrict__ bias,
    float* __restrict__ out)
{
    const int lane = threadIdx.x & 63;
    const int wid  = threadIdx.x >> 6;

    // 32768 blocks = (b,o) pairs. xcd = blk&7 owns o-band [xcd*128, xcd*128+128);
    // 32 consecutive-j blocks share one o (same XCD) -> w row fetched once per XCD.
    const int xcd = blockIdx.x & 7;
    const int j   = blockIdx.x >> 3;          // 0..4095
    const int o   = (xcd << 7) | (j >> 5);    // 128 o-rows per XCD band
    const int b   = j & 31;                   // 32 b-values

    // wave wid covers elements [wid*256, wid*256+256); lane i owns [.. +4i, +4)
    const size_t rowx = ((size_t)b * OUT_DIM + o) * IN_DIM;
    const size_t roww = (size_t)o * IN_DIM;
    const int    off  = (wid << 8) + (lane << 2);

    vfloat4 xv = *(const vfloat4*)(x + rowx + off);   // fully coalesced 1KB/wave
    vfloat4 wv = *(const vfloat4*)(w + roww + off);

    // running composed function (identity) over this lane's 4 contiguous elems.
    int rs = 0;
    int rL = -(1 << 28);
    int rU =  (1 << 28);

    float pe[4] = { xv.x * wv.x, xv.y * wv.y, xv.z * wv.z, xv.w * wv.w };
    #pragma unroll
    for (int e = 0; e < 4; ++e) {
        // quantize: v = clamp(floor(32 * (x*w)), -127, 127)
        // (x*w) rounds first (matches JAX); *32 and /32 are exact (pow2).
        float t = floorf(pe[e] * 32.0f);
        t = fminf(fmaxf(t, -127.0f), 127.0f);    // v_med3_f32
        int v = (int)t;
        // element 1023 is the scan init -> constant function (0, v, v)
        bool isInit = (wid == 3) && (lane == 63) && (e == 3);
        int sE = isInit ? 0 : v;
        int LE = isInit ? v : -127;
        int UE = isInit ? v : 127;
        // new = running ∘ elem (running outer: lower element index applied later)
        int ns = sE + rs;
        int nL = min(max(LE + rs, rL), rU);      // v_med3_i32
        int nU = min(max(UE + rs, rL), rU);
        rs = ns; rL = nL; rU = nU;
    }

    // 6-step butterfly: lane with lower index (lower elements) is the OUTER function.
    #pragma unroll
    for (int m = 1; m < 64; m <<= 1) {
        int ps = __shfl_xor(rs, m, 64);
        int pL = __shfl_xor(rL, m, 64);
        int pU = __shfl_xor(rU, m, 64);
        bool lower = ((lane & m) == 0);
        int sG = lower ? rs : ps;   // outer
        int LG = lower ? rL : pL;
        int UG = lower ? rU : pU;
        int sF = lower ? ps : rs;   // inner
        int LF = lower ? pL : rL;
        int UF = lower ? pU : rU;
        rs = sF + sG;
        rL = min(max(LF + sG, LG), UG);
        rU = min(max(UF + sG, LG), UG);
    }

    // cross-wave combine: 4 chunk functions, chunk 3 innermost (holds init).
    __shared__ int Ss[4], Sl[4], Su[4];
    if (lane == 0) { Ss[wid] = rs; Sl[wid] = rL; Su[wid] = rU; }
    __syncthreads();

    if (threadIdx.x == 0) {
        int cs = Ss[3], cL = Sl[3], cU = Su[3];          // innermost (has init)
        #pragma unroll
        for (int k = 2; k >= 0; --k) {                   // wrap with outer chunks
            int sG = Ss[k], LG = Sl[k], UG = Su[k];
            int nL = min(max(cL + sG, LG), UG);
            int nU = min(max(cU + sG, LG), UG);
            cs = cs + sG; cL = nL; cU = nU;
        }
        // cL == cU == acc (exact). Final: fix_x(acc/32 + bias) in fp32 like the ref.
        float acc = (float)cL * 0.03125f;          // exact (power of 2)
        float tb  = acc + bias[o];                 // single fp32 rounding, matches ref
        float r   = floorf(tb * 32.0f);            // *32 exact
        r = fminf(fmaxf(r, -127.0f), 127.0f);
        out[(size_t)b * OUT_DIM + o] = r * 0.03125f;
    }
}

extern "C" void kernel_launch(void* const* d_in, const int* in_sizes, int n_in,
                              void* d_out, int out_size, void* d_ws, size_t ws_size,
                              hipStream_t stream) {
    const float* x    = (const float*)d_in[0];
    const float* w    = (const float*)d_in[1];
    const float* bias = (const float*)d_in[2];
    float* out = (float*)d_out;

    const int blocks = B_DIM * OUT_DIM;    // 32768 (b,o) pairs, one block each
    ffl_kernel<<<blocks, 256, 0, stream>>>(x, w, bias, out);
}